// Round 12
// baseline (847.393 us; speedup 1.0000x reference)
//
#include <hip/hip_runtime.h>
#include <math.h>

#define D_DIM 768
#define NF    385
#define NSP   772          // 2*NF pad-to-4
#define BATCH 4
#define SEQ   4096
#define MROWS 16384
#define KP5   800          // stage-5 K padded to multiple of 32 (25 K-tiles)
#define SPECZ ((size_t)NSP * MROWS)

typedef __bf16 bf16x8 __attribute__((ext_vector_type(8)));
typedef float  f32x4  __attribute__((ext_vector_type(4)));

// async global->LDS, 16B per lane; LDS dest is wave-uniform base + lane*16
__device__ __forceinline__ void gl2lds16(const __bf16* g, __bf16* l) {
    __builtin_amdgcn_global_load_lds(
        (const __attribute__((address_space(1))) void*)g,
        (__attribute__((address_space(3))) void*)l, 16, 0, 0);
}

// ---------------------------------------------------------------------------
// Fused prologue (one dispatch, 3 independent jobs partitioned by blockIdx):
//  [0,1728): transposeW — W_z [768][768] fp32 -> WT[z][d][e] bf16
//  [1728,2240): build DFT tables FtabT [772][768] + GT [768][800]
//  [2240,3264): cvt_x — x fp32 [16384][768] -> bf16 flat
// ---------------------------------------------------------------------------
__global__ __launch_bounds__(256) void prologue(
    __bf16* __restrict__ FtabT, __bf16* __restrict__ GT,
    const float* __restrict__ W0, const float* __restrict__ W1,
    const float* __restrict__ W2, __bf16* __restrict__ WT,
    const float* __restrict__ x, __bf16* __restrict__ x16)
{
    const int bid = blockIdx.x;
    const int tid = threadIdx.x;
    if (bid < 1728) {
        // ---- transposeW ----
        __shared__ float tile[32][33];
        const int bz = bid / 576, rem = bid % 576;
        const int bx = rem % 24, by = rem / 24;
        const float* W = bz == 0 ? W0 : (bz == 1 ? W1 : W2);
        const int tx = tid & 31, ty = tid >> 5;
        const int e0 = bx * 32, d0 = by * 32;
        #pragma unroll
        for (int j = 0; j < 4; ++j)
            tile[ty + j*8][tx] = W[(size_t)(e0 + ty + j*8) * D_DIM + d0 + tx];
        __syncthreads();
        __bf16* WTz = WT + (size_t)bz * D_DIM * D_DIM;
        #pragma unroll
        for (int j = 0; j < 4; ++j)
            WTz[(size_t)(d0 + ty + j*8) * D_DIM + e0 + tx] = (__bf16)tile[tx][ty + j*8];
    } else if (bid < 2240) {
        // ---- build tables ----
        int idx = (bid - 1728) * 256 + tid;
        const int stride = 512 * 256;
        const float w0 = 6.28318530717958647692f / (float)D_DIM;
        for (int i = idx; i < NF * D_DIM; i += stride) {
            int f = i / D_DIM, e = i - f * D_DIM;
            int m = (e * f) % D_DIM;             // exact angle reduction
            float s, c;
            __sincosf(w0 * (float)m, &s, &c);
            FtabT[(size_t)(2*f)   * D_DIM + e] = (__bf16)c;
            FtabT[(size_t)(2*f+1) * D_DIM + e] = (__bf16)(-s);
            bool dcny = (f == 0) || (f == NF - 1);
            float w = dcny ? (1.0f / D_DIM) : (2.0f / D_DIM);
            GT[(size_t)e * KP5 + 2*f]     = (__bf16)(w * c);
            GT[(size_t)e * KP5 + 2*f + 1] = dcny ? (__bf16)0.0f : (__bf16)(-w * s);
        }
        for (int i = idx; i < 2 * D_DIM; i += stride)
            FtabT[(size_t)770 * D_DIM + i] = (__bf16)0.0f;
        for (int i = idx; i < D_DIM * (KP5 - 2 * NF); i += stride) {
            int r = i / (KP5 - 2 * NF), c = 2 * NF + (i % (KP5 - 2 * NF));
            GT[(size_t)r * KP5 + c] = (__bf16)0.0f;
        }
    } else {
        // ---- cvt_x ----
        int idx = (bid - 2240) * 256 + tid;
        const int stride = 1024 * 256;
        const int total8 = MROWS * D_DIM / 8;
        const float4* x4 = (const float4*)x;
        for (int i = idx; i < total8; i += stride) {
            float4 a = x4[2*i], b = x4[2*i+1];
            bf16x8 o;
            o[0]=(__bf16)a.x; o[1]=(__bf16)a.y; o[2]=(__bf16)a.z; o[3]=(__bf16)a.w;
            o[4]=(__bf16)b.x; o[5]=(__bf16)b.y; o[6]=(__bf16)b.z; o[7]=(__bf16)b.w;
            *((bf16x8*)x16 + i) = o;
        }
    }
}

// ---------------------------------------------------------------------------
// OT bf16 [772][16384] -> O bf16 [16384][800]; 64x64 tiles, 4-B packed
// accesses both sides. Rows >= 772 and O cols 772..799 read as zero.
// ---------------------------------------------------------------------------
__global__ __launch_bounds__(256) void transposeO64(
    const unsigned short* __restrict__ OT, unsigned short* __restrict__ O)
{
    __shared__ unsigned short tile[64][66];
    const int tid = threadIdx.x;
    const int m0 = blockIdx.x * 64, c0 = blockIdx.y * 64;
    const int half = tid & 31, row8 = tid >> 5;     // 32 col-pairs x 8 rows
    #pragma unroll
    for (int p = 0; p < 8; ++p) {
        const int c = c0 + p * 8 + row8;
        unsigned int v = 0;
        if (c < NSP)
            v = *(const unsigned int*)(OT + (size_t)c * MROWS + m0 + half * 2);
        *(unsigned int*)&tile[p * 8 + row8][half * 2] = v;
    }
    __syncthreads();
    #pragma unroll
    for (int p = 0; p < 8; ++p) {
        const int m = m0 + p * 8 + row8;
        const int c = c0 + half * 2;
        if (c < KP5) {
            unsigned int re = tile[half * 2][p * 8 + row8];
            unsigned int im = tile[half * 2 + 1][p * 8 + row8];
            *(unsigned int*)(O + (size_t)m * KP5 + c) = (im << 16) | re;
        }
    }
}

// ---------------------------------------------------------------------------
// bf16 NT MFMA GEMM: C[M,N] = A[M,K] @ Bt[N,K]^T
// 128x128 tile, BK=32, 4 waves (2x2 of 64x64), 16x16x32 MFMA.
// Used for the small stage-2 GEMM only.
// ---------------------------------------------------------------------------
__global__ __launch_bounds__(256) void mfma_nt(
    const __bf16* __restrict__ A, const __bf16* __restrict__ B, void* __restrict__ Cv,
    int M, int N, int K, int lda, int ldb, int ldc,
    long strideAz, long strideBz, long strideCz, int c_bf16,
    const float* __restrict__ addend, const float* __restrict__ gain)
{
    __shared__ __bf16 As[128 * 32];
    __shared__ __bf16 Bs[128 * 32];
    const int tid  = threadIdx.x;
    const int wave = tid >> 6, lane = tid & 63;
    const int lrow = lane & 15, lquad = lane >> 4;
    const int wm = wave >> 1, wn = wave & 1;
    const int m0 = blockIdx.y * 128, n0 = blockIdx.x * 128;
    const __bf16* Az = A + (size_t)blockIdx.z * strideAz;
    const __bf16* Bz = B + (size_t)blockIdx.z * strideBz;

    const int sr = tid >> 2;                               // 0..63
    const int sc = (((tid & 3) ^ ((tid >> 3) & 3))) * 8;   // swizzled K-block
    int ra0 = m0 + sr;      if (ra0 > M - 1) ra0 = M - 1;
    int ra1 = m0 + sr + 64; if (ra1 > M - 1) ra1 = M - 1;
    const int rb0 = n0 + sr, rb1 = n0 + sr + 64;
    __bf16* ldsA0 = As + wave * 512;
    __bf16* ldsA1 = As + 2048 + wave * 512;
    __bf16* ldsB0 = Bs + wave * 512;
    __bf16* ldsB1 = Bs + 2048 + wave * 512;

    const int swz = (lrow >> 1) & 3;                       // reader de-swizzle
    const int fragcol = (lquad ^ swz) * 8;

    f32x4 acc[4][4];
    #pragma unroll
    for (int i = 0; i < 4; ++i)
        #pragma unroll
        for (int j = 0; j < 4; ++j)
            acc[i][j] = (f32x4){0.f, 0.f, 0.f, 0.f};

    for (int k0 = 0; k0 < K; k0 += 32) {
        gl2lds16(Az + (size_t)ra0 * lda + k0 + sc, ldsA0);
        gl2lds16(Az + (size_t)ra1 * lda + k0 + sc, ldsA1);
        gl2lds16(Bz + (size_t)rb0 * ldb + k0 + sc, ldsB0);
        gl2lds16(Bz + (size_t)rb1 * ldb + k0 + sc, ldsB1);
        __syncthreads();
        bf16x8 af[4], bfr[4];
        #pragma unroll
        for (int i = 0; i < 4; ++i) {
            af[i]  = *(const bf16x8*)&As[(wm*64 + i*16 + lrow) * 32 + fragcol];
            bfr[i] = *(const bf16x8*)&Bs[(wn*64 + i*16 + lrow) * 32 + fragcol];
        }
        #pragma unroll
        for (int i = 0; i < 4; ++i)
            #pragma unroll
            for (int j = 0; j < 4; ++j)
                acc[i][j] = __builtin_amdgcn_mfma_f32_16x16x32_bf16(
                    af[i], bfr[j], acc[i][j], 0, 0, 0);
        __syncthreads();
    }

    // C/D layout (verified m89): col = lane&15, row = (lane>>4)*4 + reg
    const int colb = n0 + wn * 64 + lrow;
    const int rowb = m0 + wm * 64 + lquad * 4;
    if (c_bf16) {
        __bf16* C = (__bf16*)Cv + (size_t)blockIdx.z * strideCz;
        #pragma unroll
        for (int i = 0; i < 4; ++i)
            #pragma unroll
            for (int j = 0; j < 4; ++j) {
                const int col = colb + j * 16;
                #pragma unroll
                for (int r = 0; r < 4; ++r) {
                    const int mm = rowb + i * 16 + r;
                    if (mm < M) C[(size_t)mm * ldc + col] = (__bf16)acc[i][j][r];
                }
            }
    } else if (addend) {
        float* C = (float*)Cv;
        const float g = gain[0];
        #pragma unroll
        for (int i = 0; i < 4; ++i)
            #pragma unroll
            for (int j = 0; j < 4; ++j) {
                const int col = colb + j * 16;
                #pragma unroll
                for (int r = 0; r < 4; ++r) {
                    const int mm = rowb + i * 16 + r;
                    if (mm < M) {
                        const size_t off = (size_t)mm * ldc + col;
                        C[off] = addend[off] + g * acc[i][j][r];
                    }
                }
            }
    } else {
        float* C = (float*)Cv + (size_t)blockIdx.z * strideCz;
        #pragma unroll
        for (int i = 0; i < 4; ++i)
            #pragma unroll
            for (int j = 0; j < 4; ++j) {
                const int col = colb + j * 16;
                #pragma unroll
                for (int r = 0; r < 4; ++r) {
                    const int mm = rowb + i * 16 + r;
                    if (mm < M) C[(size_t)mm * ldc + col] = acc[i][j][r];
                }
            }
    }
}

// ---------------------------------------------------------------------------
// 128x256 bf16 NT MFMA GEMM, 2-buffer 2-phase split-staging, 3 blocks/CU.
// R11 change: 3buf/72KB (2 domains/CU) -> 2buf/48KB (3 domains/CU, 24
// waves/CU). Three consecutive schedule variants all measured ~77-84 us at
// 2 domains — the binding constraint is cross-block overlap (m114), so buy
// a third barrier domain with LDS.
// 8 waves (2M x 4N, per-wave 64x64, acc[4][4]), BK=32. Per tile, 2 phases:
//  q0: read A-frags(4)+B-frags jj=0,1(2); stage B(t+1)[2 ops]->buf d^1
//      (tile t-1's buffer: ALL its reads ended before the end-of-(t-1)
//      barrier); mfma acc[*][0,1]; barrier.
//  q1: read B-frags jj=2,3(2); stage A(t+2)[1 op]->buf d (A of buf d is
//      read ONLY in q0; mid-tile barrier separates); mfma acc[*][2,3];
//      vmcnt(1); barrier.
// vmcnt ledger: prologue {A0,B0x2,A1}, vmcnt(1) drains tile0, leaves A(1).
// End of tile t in-flight = {A(t+1)[t-1 q1], B(t+1)x2[t q0], A(t+2)[t q1]}
// -> vmcnt(1) drains A(t+1) (2 phases old) + B(t+1) (1.5 phases old),
// leaves A(t+2). Fast-wave t+1 staging vs slow-wave t reads: separated by
// the end-of-t barrier. Swizzle = m97 pair (2-way aliasing, free, m136).
// Grid: 1-D, ncol*nyb blocks, multiple of 8 (XCD swizzle).
// [resubmission: round-11 bench was an infra failure, no counters returned]
// ---------------------------------------------------------------------------
__global__ __launch_bounds__(512, 6) void mfma_nt256(
    const __bf16* __restrict__ A, const __bf16* __restrict__ B,
    void* __restrict__ Cv, int M, int N, int K,
    int lda, int ldb, int ldc, int nyb, int c_bf16,
    const float* __restrict__ addend, const float* __restrict__ gain)
{
    __shared__ __bf16 lds[24576];          // 48 KiB
    __bf16* AsBase = lds;                  // 2 x [128][32]
    __bf16* BsBase = lds + 8192;           // 2 x [256][32]

    const int tid  = threadIdx.x;
    const int wave = tid >> 6, lane = tid & 63;
    const int lrow = lane & 15, lq = lane >> 4;
    const int wm = wave >> 2, wn = wave & 3;  // 2M x 4N waves

    // XCD-aware bijective swizzle (gridDim.x % 8 == 0 guaranteed by caller)
    const int cpx = gridDim.x >> 3;
    const int swz = (blockIdx.x & 7) * cpx + (blockIdx.x >> 3);
    const int bx = swz / nyb, by = swz - bx * nyb;
    const int m0 = by * 128, n0 = bx * 256;
    const int NT = K >> 5;

    // ---- staging constants (1 gl2lds op per thread per 128-row panel) ----
    const int srow = tid >> 2;                          // 0..127
    const int skc  = ((tid & 3) ^ ((tid >> 3) & 3)) * 8;  // inv-swizzled src col
    const int sdst = wave << 9;                         // wave-uniform, elems

    auto stageA = [&](int t, int buf) {
        __bf16* slot = AsBase + buf * 4096;
        int gr = m0 + srow;
        if (gr > M - 1) gr = M - 1;                     // M-tail clamp
        gl2lds16(A + (size_t)gr * lda + (t << 5) + skc, slot + sdst);
    };
    auto stageB = [&](int t, int buf) {
        __bf16* slot = BsBase + buf * 8192;
        #pragma unroll
        for (int h = 0; h < 2; ++h) {
            const int gr = n0 + h * 128 + srow;
            gl2lds16(B + (size_t)gr * ldb + (t << 5) + skc,
                     slot + h * 4096 + sdst);
        }
    };

    // ---- fragment-read constants ----
    const int kx   = (lq ^ ((lrow >> 1) & 3)) * 8;      // swizzled read col
    const int aoff = wm * 2048 + lrow * 32 + kx;
    const int boff = wn * 2048 + lrow * 32 + kx;

    bf16x8 Af[4], Bf[2];
    f32x4 acc[4][4];
    #pragma unroll
    for (int i = 0; i < 4; ++i)
        #pragma unroll
        for (int j = 0; j < 4; ++j)
            acc[i][j] = (f32x4){0.f, 0.f, 0.f, 0.f};

    // ---- prologue: A(0),B(0) -> buf0; A(1) -> buf1; leave A(1) in flight ----
    stageA(0, 0); stageB(0, 0);
    if (NT > 1) {
        stageA(1, 1);
        asm volatile("s_waitcnt vmcnt(1)" ::: "memory");
    } else {
        asm volatile("s_waitcnt vmcnt(0)" ::: "memory");
    }
    __builtin_amdgcn_s_barrier();
    __builtin_amdgcn_sched_barrier(0);

    // ---- main loop: 2 phases + 2 barriers per K-tile ----
    for (int t = 0; t < NT; ++t) {
        const int d = t & 1;
        const __bf16* Ard = AsBase + d * 4096;
        const __bf16* Brd = BsBase + d * 8192;
        const bool p1 = (t + 1 < NT), p2 = (t + 2 < NT);

        // q0: columns jj=0,1; stage B(t+1) -> buf d^1 (tile t-1's, fully read)
        #pragma unroll
        for (int ii = 0; ii < 4; ++ii)
            Af[ii] = *(const bf16x8*)(Ard + aoff + ii * 512);
        Bf[0] = *(const bf16x8*)(Brd + boff);
        Bf[1] = *(const bf16x8*)(Brd + boff + 512);
        if (p1) stageB(t + 1, d ^ 1);
        __builtin_amdgcn_s_setprio(1);
        #pragma unroll
        for (int ii = 0; ii < 4; ++ii)
            #pragma unroll
            for (int jj = 0; jj < 2; ++jj)
                acc[ii][jj] = __builtin_amdgcn_mfma_f32_16x16x32_bf16(
                    Af[ii], Bf[jj], acc[ii][jj], 0, 0, 0);
        __builtin_amdgcn_s_setprio(0);
        __builtin_amdgcn_s_barrier();

        // q1: columns jj=2,3 (reuse Af); stage A(t+2) -> buf d (A read only
        // in q0, barrier-separated).
        Bf[0] = *(const bf16x8*)(Brd + boff + 1024);
        Bf[1] = *(const bf16x8*)(Brd + boff + 1536);
        if (p2) stageA(t + 2, d);
        __builtin_amdgcn_s_setprio(1);
        #pragma unroll
        for (int ii = 0; ii < 4; ++ii)
            #pragma unroll
            for (int jj = 0; jj < 2; ++jj)
                acc[ii][2 + jj] = __builtin_amdgcn_mfma_f32_16x16x32_bf16(
                    Af[ii], Bf[jj], acc[ii][2 + jj], 0, 0, 0);
        __builtin_amdgcn_s_setprio(0);
        if (p2)      asm volatile("s_waitcnt vmcnt(1)" ::: "memory");
        else if (p1) asm volatile("s_waitcnt vmcnt(0)" ::: "memory");
        __builtin_amdgcn_s_barrier();
        __builtin_amdgcn_sched_barrier(0);
    }

    // ---- epilogue: C/D layout col = lane&15, row = (lane>>4)*4 + reg ----
    const int colb = n0 + wn * 64 + lrow;
    const int rowb = m0 + wm * 64 + lq * 4;
    if (c_bf16) {
        __bf16* C = (__bf16*)Cv;
        #pragma unroll
        for (int i = 0; i < 4; ++i)
            #pragma unroll
            for (int j = 0; j < 4; ++j) {
                const int col = colb + j * 16;
                #pragma unroll
                for (int r = 0; r < 4; ++r) {
                    const int mm = rowb + i * 16 + r;
                    if (mm < M) C[(size_t)mm * ldc + col] = (__bf16)acc[i][j][r];
                }
            }
    } else {
        float* C = (float*)Cv;
        const float g = gain[0];
        #pragma unroll
        for (int i = 0; i < 4; ++i)
            #pragma unroll
            for (int j = 0; j < 4; ++j) {
                const int col = colb + j * 16;
                #pragma unroll
                for (int r = 0; r < 4; ++r) {
                    const int mm = rowb + i * 16 + r;
                    if (mm < M) {
                        const size_t off = (size_t)mm * ldc + col;
                        C[off] = addend[off] + g * acc[i][j][r];
                    }
                }
            }
    }
}

// ---------------------------------------------------------------------------
// Causal complex scan over bf16 spectra (transposed layout), in place over K.
// One block per (b,f) chain; thread t owns 16 consecutive s.
// ---------------------------------------------------------------------------
__global__ __launch_bounds__(256) void scan_blocks(__bf16* __restrict__ spec) {
    const int blk = blockIdx.x;
    const int b = blk / NF, f = blk % NF;
    const int tid = threadIdx.x;
    const int lane = tid & 63, wid = tid >> 6;
    const size_t colbase = (size_t)b * SEQ;
    __bf16* Kre = spec + (size_t)(2*f) * MROWS + colbase;
    __bf16* Kim = Kre + MROWS;
    const __bf16* Vre = Kre + SPECZ;
    const __bf16* Vim = Vre + MROWS;
    const __bf16* Qre = Kre + 2 * SPECZ;
    const __bf16* Qim = Qre + MROWS;
    const int s0 = tid * 16;

    bf16x8 kr0 = *(const bf16x8*)(Kre + s0), kr1 = *(const bf16x8*)(Kre + s0 + 8);
    bf16x8 ki0 = *(const bf16x8*)(Kim + s0), ki1 = *(const bf16x8*)(Kim + s0 + 8);
    bf16x8 vr0 = *(const bf16x8*)(Vre + s0), vr1 = *(const bf16x8*)(Vre + s0 + 8);
    bf16x8 vi0 = *(const bf16x8*)(Vim + s0), vi1 = *(const bf16x8*)(Vim + s0 + 8);

    float pr[16], pi[16];
    #pragma unroll
    for (int u = 0; u < 8; ++u) {
        float a = (float)kr0[u], bq = (float)ki0[u], c = (float)vr0[u], d = (float)vi0[u];
        pr[u] = a * c - bq * d;
        pi[u] = a * d + bq * c;
        float a1 = (float)kr1[u], b1 = (float)ki1[u], c1 = (float)vr1[u], d1 = (float)vi1[u];
        pr[8+u] = a1 * c1 - b1 * d1;
        pi[8+u] = a1 * d1 + b1 * c1;
    }
    #pragma unroll
    for (int j = 1; j < 16; ++j) { pr[j] += pr[j-1]; pi[j] += pi[j-1]; }
    const float totr = pr[15], toti = pi[15];

    float sr = totr, si = toti;
    #pragma unroll
    for (int d = 1; d < 64; d <<= 1) {
        float ur = __shfl_up(sr, d, 64);
        float ui = __shfl_up(si, d, 64);
        if (lane >= d) { sr += ur; si += ui; }
    }
    __shared__ float wsr[4], wsi[4];
    if (lane == 63) { wsr[wid] = sr; wsi[wid] = si; }
    __syncthreads();
    float baser = 0.f, basei = 0.f;
    #pragma unroll
    for (int w = 0; w < 3; ++w)
        if (w < wid) { baser += wsr[w]; basei += wsi[w]; }
    const float exr = baser + sr - totr;
    const float exi = basei + si - toti;

    bf16x8 qr0 = *(const bf16x8*)(Qre + s0), qr1 = *(const bf16x8*)(Qre + s0 + 8);
    bf16x8 qi0 = *(const bf16x8*)(Qim + s0), qi1 = *(const bf16x8*)(Qim + s0 + 8);
    bf16x8 outr0, outr1, outi0, outi1;
    #pragma unroll
    for (int u = 0; u < 8; ++u) {
        float mr = exr + pr[u],   mi = exi + pi[u];
        float qr = (float)qr0[u], qi = (float)qi0[u];
        outr0[u] = (__bf16)(mr * qr + mi * qi);
        outi0[u] = (__bf16)(mi * qr - mr * qi);
        float mr1 = exr + pr[8+u], mi1 = exi + pi[8+u];
        float qr_ = (float)qr1[u], qi_ = (float)qi1[u];
        outr1[u] = (__bf16)(mr1 * qr_ + mi1 * qi_);
        outi1[u] = (__bf16)(mi1 * qr_ - mr1 * qi_);
    }
    *(bf16x8*)(Kre + s0)     = outr0;
    *(bf16x8*)(Kre + s0 + 8) = outr1;
    *(bf16x8*)(Kim + s0)     = outi0;
    *(bf16x8*)(Kim + s0 + 8) = outi1;
}

// ---------------------------------------------------------------------------
// Workspace (bf16): FtabT[772*768] | GT[768*800] | WT[3*768*768]
//  | x16[16384*768] | CTs[2316*768] | spec[3*772*16384]; O overlays specV/Q.
// ---------------------------------------------------------------------------
extern "C" void kernel_launch(void* const* d_in, const int* in_sizes, int n_in,
                              void* d_out, int out_size, void* d_ws, size_t ws_size,
                              hipStream_t stream) {
    const float* x    = (const float*)d_in[0];
    const float* Wk   = (const float*)d_in[1];
    const float* Wv   = (const float*)d_in[2];
    const float* Wq   = (const float*)d_in[3];
    const float* gain = (const float*)d_in[4];
    float* out = (float*)d_out;

    __bf16* FtabT = (__bf16*)d_ws;
    __bf16* GT    = FtabT + (size_t)NSP * D_DIM;
    __bf16* WT    = GT    + (size_t)D_DIM * KP5;
    __bf16* x16   = WT    + (size_t)3 * D_DIM * D_DIM;
    __bf16* CTs   = x16   + (size_t)MROWS * D_DIM;
    __bf16* spec  = CTs   + (size_t)3 * NSP * D_DIM;
    __bf16* O     = spec  + SPECZ;   // over specV/specQ (free after scan)

    // prologue: tables + W transposes + x conversion (one dispatch)
    prologue<<<3264, 256, 0, stream>>>(FtabT, GT, Wk, Wv, Wq, WT, x, x16);

    // stage 2: CTs[z*772+c][e] = FtabT @ WT_z^T  (z-batched, stacked in M)
    mfma_nt<<<dim3(6, 7, 3), 256, 0, stream>>>(
        FtabT, WT, CTs, NSP, D_DIM, D_DIM,
        D_DIM, D_DIM, D_DIM,
        0L, (long)D_DIM * D_DIM, (long)NSP * D_DIM, 1, nullptr, nullptr);

    // stage 3: spec[2316][16384] = CTs @ x16^T — 128x256, 3 blocks/CU.
    // grid = 64 col-blocks x 19 row-blocks = 1216 (multiple of 8 for T1).
    mfma_nt256<<<dim3(64 * 19), 512, 0, stream>>>(
        CTs, x16, spec, 3 * NSP, MROWS, D_DIM,
        D_DIM, D_DIM, MROWS, 19, 1, nullptr, nullptr);

    // stage 4: causal binding scan + unbind (in place over specK)
    scan_blocks<<<BATCH * NF, 256, 0, stream>>>(spec);

    // OT -> O bf16 [16384][800] (zero-padded cols)
    transposeO64<<<dim3(MROWS / 64, 13), 256, 0, stream>>>(
        (const unsigned short*)spec, (unsigned short*)O);

    // stage 5: out[16384][768] = x + gain * (O @ GT^T) — same kernel.
    // grid = 3 col-blocks x 128 row-blocks = 384; all blocks co-resident.
    mfma_nt256<<<dim3(3 * 128), 512, 0, stream>>>(
        O, GT, out, MROWS, D_DIM, KP5,
        KP5, KP5, D_DIM, 128, 0, x, gain);
}

// Round 13
// 272.739 us; speedup vs baseline: 3.1070x; 3.1070x over previous
//
#include <hip/hip_runtime.h>
#include <math.h>

#define D_DIM 768
#define NF    385
#define NSP   772          // 2*NF pad-to-4
#define BATCH 4
#define SEQ   4096
#define MROWS 16384
#define KP5   800          // stage-5 K padded to multiple of 32 (25 K-tiles)
#define SPECZ ((size_t)NSP * MROWS)

typedef __bf16 bf16x8 __attribute__((ext_vector_type(8)));
typedef float  f32x4  __attribute__((ext_vector_type(4)));

// async global->LDS, 16B per lane; LDS dest is wave-uniform base + lane*16
__device__ __forceinline__ void gl2lds16(const __bf16* g, __bf16* l) {
    __builtin_amdgcn_global_load_lds(
        (const __attribute__((address_space(1))) void*)g,
        (__attribute__((address_space(3))) void*)l, 16, 0, 0);
}

// ---------------------------------------------------------------------------
// Fused prologue (one dispatch, 3 independent jobs partitioned by blockIdx):
//  [0,1728): transposeW — W_z [768][768] fp32 -> WT[z][d][e] bf16
//  [1728,2240): build DFT tables FtabT [772][768] + GT [768][800]
//  [2240,3264): cvt_x — x fp32 [16384][768] -> bf16 flat
// ---------------------------------------------------------------------------
__global__ __launch_bounds__(256) void prologue(
    __bf16* __restrict__ FtabT, __bf16* __restrict__ GT,
    const float* __restrict__ W0, const float* __restrict__ W1,
    const float* __restrict__ W2, __bf16* __restrict__ WT,
    const float* __restrict__ x, __bf16* __restrict__ x16)
{
    const int bid = blockIdx.x;
    const int tid = threadIdx.x;
    if (bid < 1728) {
        // ---- transposeW ----
        __shared__ float tile[32][33];
        const int bz = bid / 576, rem = bid % 576;
        const int bx = rem % 24, by = rem / 24;
        const float* W = bz == 0 ? W0 : (bz == 1 ? W1 : W2);
        const int tx = tid & 31, ty = tid >> 5;
        const int e0 = bx * 32, d0 = by * 32;
        #pragma unroll
        for (int j = 0; j < 4; ++j)
            tile[ty + j*8][tx] = W[(size_t)(e0 + ty + j*8) * D_DIM + d0 + tx];
        __syncthreads();
        __bf16* WTz = WT + (size_t)bz * D_DIM * D_DIM;
        #pragma unroll
        for (int j = 0; j < 4; ++j)
            WTz[(size_t)(d0 + ty + j*8) * D_DIM + e0 + tx] = (__bf16)tile[tx][ty + j*8];
    } else if (bid < 2240) {
        // ---- build tables ----
        int idx = (bid - 1728) * 256 + tid;
        const int stride = 512 * 256;
        const float w0 = 6.28318530717958647692f / (float)D_DIM;
        for (int i = idx; i < NF * D_DIM; i += stride) {
            int f = i / D_DIM, e = i - f * D_DIM;
            int m = (e * f) % D_DIM;             // exact angle reduction
            float s, c;
            __sincosf(w0 * (float)m, &s, &c);
            FtabT[(size_t)(2*f)   * D_DIM + e] = (__bf16)c;
            FtabT[(size_t)(2*f+1) * D_DIM + e] = (__bf16)(-s);
            bool dcny = (f == 0) || (f == NF - 1);
            float w = dcny ? (1.0f / D_DIM) : (2.0f / D_DIM);
            GT[(size_t)e * KP5 + 2*f]     = (__bf16)(w * c);
            GT[(size_t)e * KP5 + 2*f + 1] = dcny ? (__bf16)0.0f : (__bf16)(-w * s);
        }
        for (int i = idx; i < 2 * D_DIM; i += stride)
            FtabT[(size_t)770 * D_DIM + i] = (__bf16)0.0f;
        for (int i = idx; i < D_DIM * (KP5 - 2 * NF); i += stride) {
            int r = i / (KP5 - 2 * NF), c = 2 * NF + (i % (KP5 - 2 * NF));
            GT[(size_t)r * KP5 + c] = (__bf16)0.0f;
        }
    } else {
        // ---- cvt_x ----
        int idx = (bid - 2240) * 256 + tid;
        const int stride = 1024 * 256;
        const int total8 = MROWS * D_DIM / 8;
        const float4* x4 = (const float4*)x;
        for (int i = idx; i < total8; i += stride) {
            float4 a = x4[2*i], b = x4[2*i+1];
            bf16x8 o;
            o[0]=(__bf16)a.x; o[1]=(__bf16)a.y; o[2]=(__bf16)a.z; o[3]=(__bf16)a.w;
            o[4]=(__bf16)b.x; o[5]=(__bf16)b.y; o[6]=(__bf16)b.z; o[7]=(__bf16)b.w;
            *((bf16x8*)x16 + i) = o;
        }
    }
}

// ---------------------------------------------------------------------------
// OT bf16 [772][16384] -> O bf16 [16384][800]; 64x64 tiles, 4-B packed
// accesses both sides. Rows >= 772 and O cols 772..799 read as zero.
// ---------------------------------------------------------------------------
__global__ __launch_bounds__(256) void transposeO64(
    const unsigned short* __restrict__ OT, unsigned short* __restrict__ O)
{
    __shared__ unsigned short tile[64][66];
    const int tid = threadIdx.x;
    const int m0 = blockIdx.x * 64, c0 = blockIdx.y * 64;
    const int half = tid & 31, row8 = tid >> 5;     // 32 col-pairs x 8 rows
    #pragma unroll
    for (int p = 0; p < 8; ++p) {
        const int c = c0 + p * 8 + row8;
        unsigned int v = 0;
        if (c < NSP)
            v = *(const unsigned int*)(OT + (size_t)c * MROWS + m0 + half * 2);
        *(unsigned int*)&tile[p * 8 + row8][half * 2] = v;
    }
    __syncthreads();
    #pragma unroll
    for (int p = 0; p < 8; ++p) {
        const int m = m0 + p * 8 + row8;
        const int c = c0 + half * 2;
        if (c < KP5) {
            unsigned int re = tile[half * 2][p * 8 + row8];
            unsigned int im = tile[half * 2 + 1][p * 8 + row8];
            *(unsigned int*)(O + (size_t)m * KP5 + c) = (im << 16) | re;
        }
    }
}

// ---------------------------------------------------------------------------
// bf16 NT MFMA GEMM: C[M,N] = A[M,K] @ Bt[N,K]^T
// 128x128 tile, BK=32, 4 waves (2x2 of 64x64), 16x16x32 MFMA.
// Used for the small stage-2 GEMM only.
// ---------------------------------------------------------------------------
__global__ __launch_bounds__(256) void mfma_nt(
    const __bf16* __restrict__ A, const __bf16* __restrict__ B, void* __restrict__ Cv,
    int M, int N, int K, int lda, int ldb, int ldc,
    long strideAz, long strideBz, long strideCz, int c_bf16,
    const float* __restrict__ addend, const float* __restrict__ gain)
{
    __shared__ __bf16 As[128 * 32];
    __shared__ __bf16 Bs[128 * 32];
    const int tid  = threadIdx.x;
    const int wave = tid >> 6, lane = tid & 63;
    const int lrow = lane & 15, lquad = lane >> 4;
    const int wm = wave >> 1, wn = wave & 1;
    const int m0 = blockIdx.y * 128, n0 = blockIdx.x * 128;
    const __bf16* Az = A + (size_t)blockIdx.z * strideAz;
    const __bf16* Bz = B + (size_t)blockIdx.z * strideBz;

    const int sr = tid >> 2;                               // 0..63
    const int sc = (((tid & 3) ^ ((tid >> 3) & 3))) * 8;   // swizzled K-block
    int ra0 = m0 + sr;      if (ra0 > M - 1) ra0 = M - 1;
    int ra1 = m0 + sr + 64; if (ra1 > M - 1) ra1 = M - 1;
    const int rb0 = n0 + sr, rb1 = n0 + sr + 64;
    __bf16* ldsA0 = As + wave * 512;
    __bf16* ldsA1 = As + 2048 + wave * 512;
    __bf16* ldsB0 = Bs + wave * 512;
    __bf16* ldsB1 = Bs + 2048 + wave * 512;

    const int swz = (lrow >> 1) & 3;                       // reader de-swizzle
    const int fragcol = (lquad ^ swz) * 8;

    f32x4 acc[4][4];
    #pragma unroll
    for (int i = 0; i < 4; ++i)
        #pragma unroll
        for (int j = 0; j < 4; ++j)
            acc[i][j] = (f32x4){0.f, 0.f, 0.f, 0.f};

    for (int k0 = 0; k0 < K; k0 += 32) {
        gl2lds16(Az + (size_t)ra0 * lda + k0 + sc, ldsA0);
        gl2lds16(Az + (size_t)ra1 * lda + k0 + sc, ldsA1);
        gl2lds16(Bz + (size_t)rb0 * ldb + k0 + sc, ldsB0);
        gl2lds16(Bz + (size_t)rb1 * ldb + k0 + sc, ldsB1);
        __syncthreads();
        bf16x8 af[4], bfr[4];
        #pragma unroll
        for (int i = 0; i < 4; ++i) {
            af[i]  = *(const bf16x8*)&As[(wm*64 + i*16 + lrow) * 32 + fragcol];
            bfr[i] = *(const bf16x8*)&Bs[(wn*64 + i*16 + lrow) * 32 + fragcol];
        }
        #pragma unroll
        for (int i = 0; i < 4; ++i)
            #pragma unroll
            for (int j = 0; j < 4; ++j)
                acc[i][j] = __builtin_amdgcn_mfma_f32_16x16x32_bf16(
                    af[i], bfr[j], acc[i][j], 0, 0, 0);
        __syncthreads();
    }

    // C/D layout (verified m89): col = lane&15, row = (lane>>4)*4 + reg
    const int colb = n0 + wn * 64 + lrow;
    const int rowb = m0 + wm * 64 + lquad * 4;
    if (c_bf16) {
        __bf16* C = (__bf16*)Cv + (size_t)blockIdx.z * strideCz;
        #pragma unroll
        for (int i = 0; i < 4; ++i)
            #pragma unroll
            for (int j = 0; j < 4; ++j) {
                const int col = colb + j * 16;
                #pragma unroll
                for (int r = 0; r < 4; ++r) {
                    const int mm = rowb + i * 16 + r;
                    if (mm < M) C[(size_t)mm * ldc + col] = (__bf16)acc[i][j][r];
                }
            }
    } else if (addend) {
        float* C = (float*)Cv;
        const float g = gain[0];
        #pragma unroll
        for (int i = 0; i < 4; ++i)
            #pragma unroll
            for (int j = 0; j < 4; ++j) {
                const int col = colb + j * 16;
                #pragma unroll
                for (int r = 0; r < 4; ++r) {
                    const int mm = rowb + i * 16 + r;
                    if (mm < M) {
                        const size_t off = (size_t)mm * ldc + col;
                        C[off] = addend[off] + g * acc[i][j][r];
                    }
                }
            }
    } else {
        float* C = (float*)Cv + (size_t)blockIdx.z * strideCz;
        #pragma unroll
        for (int i = 0; i < 4; ++i)
            #pragma unroll
            for (int j = 0; j < 4; ++j) {
                const int col = colb + j * 16;
                #pragma unroll
                for (int r = 0; r < 4; ++r) {
                    const int mm = rowb + i * 16 + r;
                    if (mm < M) C[(size_t)mm * ldc + col] = acc[i][j][r];
                }
            }
    }
}

// ---------------------------------------------------------------------------
// 128x256 bf16 NT MFMA GEMM, triple-buffered 2-tile-deep prefetch, 2 blk/CU.
// R10-verified best (stage-3 77 us, total 271 us). R12 lesson locked in:
// pushing to 3 blocks/CU via __launch_bounds__(512,6) caps regs at ~85/wave
// < the 64-reg accumulator + frags -> acc spills to scratch (VGPR_Count 40,
// FETCH 11x, WRITE 18x, MfmaUtil 4.8%, 501 us). (512,4) = 128 regs is the
// minimum viable budget for this tile shape; keep it.
// 8 waves (2M x 4N, per-wave 64x64, acc[4][4]=64 AGPR), BK=32, 72 KiB LDS
// (A: 3 buf x 128x32 = 24 KB; B: 3 buf x 256x32 = 48 KB), 3 DMA ops/tile
// (A=1, B=2), ONE barrier per K-tile. Tile t stages tile t+2 into buf
// (t+2)%3 (t>=1; prologue staged tiles 0,1,2).
// vmcnt ledger: prologue 9 ops, vmcnt(6) lands tile 0; at each tile end
// in-flight = {t+1,t+2} = 6 -> vmcnt(3) drains t+1 (issued 2 tiles ago).
// Hazard: buf (t+2)%3 is read only by tiles t-1 (past barrier) and t+2
// (two barriers ahead); fast-wave DMA vs slow-wave reads covered by the
// per-tile barrier.  Swizzle = m97 pair (2-way bank aliasing, free, m136).
// Grid: 1-D, ncol*nyb blocks, multiple of 8 (XCD swizzle); consecutive
// swizzled blocks share the B panel (same bx) for L2 locality.
// ---------------------------------------------------------------------------
__global__ __launch_bounds__(512, 4) void mfma_nt256(
    const __bf16* __restrict__ A, const __bf16* __restrict__ B,
    void* __restrict__ Cv, int M, int N, int K,
    int lda, int ldb, int ldc, int nyb, int c_bf16,
    const float* __restrict__ addend, const float* __restrict__ gain)
{
    __shared__ __bf16 lds[36864];          // 72 KiB
    __bf16* AsBase = lds;                  // 3 x [128][32]
    __bf16* BsBase = lds + 12288;          // 3 x [256][32]

    const int tid  = threadIdx.x;
    const int wave = tid >> 6, lane = tid & 63;
    const int lrow = lane & 15, lq = lane >> 4;
    const int wm = wave >> 2, wn = wave & 3;  // 2M x 4N waves

    // XCD-aware bijective swizzle (gridDim.x % 8 == 0 guaranteed by caller)
    const int cpx = gridDim.x >> 3;
    const int swz = (blockIdx.x & 7) * cpx + (blockIdx.x >> 3);
    const int bx = swz / nyb, by = swz - bx * nyb;
    const int m0 = by * 128, n0 = bx * 256;
    const int NT = K >> 5;

    // ---- staging constants (1 gl2lds op per thread per 128-row panel) ----
    const int srow = tid >> 2;                          // 0..127
    const int skc  = ((tid & 3) ^ ((tid >> 3) & 3)) * 8;  // inv-swizzled src col
    const int sdst = wave << 9;                         // wave-uniform, elems

    auto stageA = [&](int t, int buf) {
        __bf16* slot = AsBase + buf * 4096;
        int gr = m0 + srow;
        if (gr > M - 1) gr = M - 1;                     // M-tail clamp
        gl2lds16(A + (size_t)gr * lda + (t << 5) + skc, slot + sdst);
    };
    auto stageB = [&](int t, int buf) {
        __bf16* slot = BsBase + buf * 8192;
        #pragma unroll
        for (int h = 0; h < 2; ++h) {
            const int gr = n0 + h * 128 + srow;
            gl2lds16(B + (size_t)gr * ldb + (t << 5) + skc,
                     slot + h * 4096 + sdst);
        }
    };

    // ---- fragment-read constants ----
    const int kx   = (lq ^ ((lrow >> 1) & 3)) * 8;      // swizzled read col
    const int aoff = wm * 2048 + lrow * 32 + kx;
    const int boff = wn * 2048 + lrow * 32 + kx;

    bf16x8 Af[4], Bf[4];
    f32x4 acc[4][4];
    #pragma unroll
    for (int i = 0; i < 4; ++i)
        #pragma unroll
        for (int j = 0; j < 4; ++j)
            acc[i][j] = (f32x4){0.f, 0.f, 0.f, 0.f};

    // ---- prologue: stage tiles 0,1,2 into bufs 0,1,2; wait tile0 only ----
    stageA(0, 0); stageB(0, 0);
    if (NT > 1) { stageA(1, 1); stageB(1, 1); }
    if (NT > 2) { stageA(2, 2); stageB(2, 2); }
    if (NT > 2)      asm volatile("s_waitcnt vmcnt(6)" ::: "memory");
    else if (NT > 1) asm volatile("s_waitcnt vmcnt(3)" ::: "memory");
    else             asm volatile("s_waitcnt vmcnt(0)" ::: "memory");
    __builtin_amdgcn_s_barrier();
    __builtin_amdgcn_sched_barrier(0);

    // ---- main loop: 1 phase + 1 barrier per K-tile ----
    int br = 0;                                         // buffer of tile t
    for (int t = 0; t < NT; ++t) {
        const __bf16* Ard = AsBase + br * 4096;
        const __bf16* Brd = BsBase + br * 8192;

        #pragma unroll
        for (int ii = 0; ii < 4; ++ii)
            Af[ii] = *(const bf16x8*)(Ard + aoff + ii * 512);
        #pragma unroll
        for (int jj = 0; jj < 4; ++jj)
            Bf[jj] = *(const bf16x8*)(Brd + boff + jj * 512);

        if (t > 0 && t + 2 < NT) {                      // tile 2 staged in prologue
            int b2 = br + 2; if (b2 >= 3) b2 -= 3;      // buf of t+2
            stageA(t + 2, b2); stageB(t + 2, b2);
        }

        __builtin_amdgcn_s_setprio(1);
        #pragma unroll
        for (int ii = 0; ii < 4; ++ii)
            #pragma unroll
            for (int jj = 0; jj < 4; ++jj)
                acc[ii][jj] = __builtin_amdgcn_mfma_f32_16x16x32_bf16(
                    Af[ii], Bf[jj], acc[ii][jj], 0, 0, 0);
        __builtin_amdgcn_s_setprio(0);

        if (t + 2 < NT)      asm volatile("s_waitcnt vmcnt(3)" ::: "memory");
        else if (t + 1 < NT) asm volatile("s_waitcnt vmcnt(0)" ::: "memory");
        __builtin_amdgcn_s_barrier();
        __builtin_amdgcn_sched_barrier(0);
        ++br; if (br >= 3) br -= 3;
    }

    // ---- epilogue: C/D layout col = lane&15, row = (lane>>4)*4 + reg ----
    const int colb = n0 + wn * 64 + lrow;
    const int rowb = m0 + wm * 64 + lq * 4;
    if (c_bf16) {
        __bf16* C = (__bf16*)Cv;
        #pragma unroll
        for (int i = 0; i < 4; ++i)
            #pragma unroll
            for (int j = 0; j < 4; ++j) {
                const int col = colb + j * 16;
                #pragma unroll
                for (int r = 0; r < 4; ++r) {
                    const int mm = rowb + i * 16 + r;
                    if (mm < M) C[(size_t)mm * ldc + col] = (__bf16)acc[i][j][r];
                }
            }
    } else {
        float* C = (float*)Cv;
        const float g = gain[0];
        #pragma unroll
        for (int i = 0; i < 4; ++i)
            #pragma unroll
            for (int j = 0; j < 4; ++j) {
                const int col = colb + j * 16;
                #pragma unroll
                for (int r = 0; r < 4; ++r) {
                    const int mm = rowb + i * 16 + r;
                    if (mm < M) {
                        const size_t off = (size_t)mm * ldc + col;
                        C[off] = addend[off] + g * acc[i][j][r];
                    }
                }
            }
    }
}

// ---------------------------------------------------------------------------
// Causal complex scan over bf16 spectra (transposed layout), in place over K.
// One block per (b,f) chain; thread t owns 16 consecutive s.
// ---------------------------------------------------------------------------
__global__ __launch_bounds__(256) void scan_blocks(__bf16* __restrict__ spec) {
    const int blk = blockIdx.x;
    const int b = blk / NF, f = blk % NF;
    const int tid = threadIdx.x;
    const int lane = tid & 63, wid = tid >> 6;
    const size_t colbase = (size_t)b * SEQ;
    __bf16* Kre = spec + (size_t)(2*f) * MROWS + colbase;
    __bf16* Kim = Kre + MROWS;
    const __bf16* Vre = Kre + SPECZ;
    const __bf16* Vim = Vre + MROWS;
    const __bf16* Qre = Kre + 2 * SPECZ;
    const __bf16* Qim = Qre + MROWS;
    const int s0 = tid * 16;

    bf16x8 kr0 = *(const bf16x8*)(Kre + s0), kr1 = *(const bf16x8*)(Kre + s0 + 8);
    bf16x8 ki0 = *(const bf16x8*)(Kim + s0), ki1 = *(const bf16x8*)(Kim + s0 + 8);
    bf16x8 vr0 = *(const bf16x8*)(Vre + s0), vr1 = *(const bf16x8*)(Vre + s0 + 8);
    bf16x8 vi0 = *(const bf16x8*)(Vim + s0), vi1 = *(const bf16x8*)(Vim + s0 + 8);

    float pr[16], pi[16];
    #pragma unroll
    for (int u = 0; u < 8; ++u) {
        float a = (float)kr0[u], bq = (float)ki0[u], c = (float)vr0[u], d = (float)vi0[u];
        pr[u] = a * c - bq * d;
        pi[u] = a * d + bq * c;
        float a1 = (float)kr1[u], b1 = (float)ki1[u], c1 = (float)vr1[u], d1 = (float)vi1[u];
        pr[8+u] = a1 * c1 - b1 * d1;
        pi[8+u] = a1 * d1 + b1 * c1;
    }
    #pragma unroll
    for (int j = 1; j < 16; ++j) { pr[j] += pr[j-1]; pi[j] += pi[j-1]; }
    const float totr = pr[15], toti = pi[15];

    float sr = totr, si = toti;
    #pragma unroll
    for (int d = 1; d < 64; d <<= 1) {
        float ur = __shfl_up(sr, d, 64);
        float ui = __shfl_up(si, d, 64);
        if (lane >= d) { sr += ur; si += ui; }
    }
    __shared__ float wsr[4], wsi[4];
    if (lane == 63) { wsr[wid] = sr; wsi[wid] = si; }
    __syncthreads();
    float baser = 0.f, basei = 0.f;
    #pragma unroll
    for (int w = 0; w < 3; ++w)
        if (w < wid) { baser += wsr[w]; basei += wsi[w]; }
    const float exr = baser + sr - totr;
    const float exi = basei + si - toti;

    bf16x8 qr0 = *(const bf16x8*)(Qre + s0), qr1 = *(const bf16x8*)(Qre + s0 + 8);
    bf16x8 qi0 = *(const bf16x8*)(Qim + s0), qi1 = *(const bf16x8*)(Qim + s0 + 8);
    bf16x8 outr0, outr1, outi0, outi1;
    #pragma unroll
    for (int u = 0; u < 8; ++u) {
        float mr = exr + pr[u],   mi = exi + pi[u];
        float qr = (float)qr0[u], qi = (float)qi0[u];
        outr0[u] = (__bf16)(mr * qr + mi * qi);
        outi0[u] = (__bf16)(mi * qr - mr * qi);
        float mr1 = exr + pr[8+u], mi1 = exi + pi[8+u];
        float qr_ = (float)qr1[u], qi_ = (float)qi1[u];
        outr1[u] = (__bf16)(mr1 * qr_ + mi1 * qi_);
        outi1[u] = (__bf16)(mi1 * qr_ - mr1 * qi_);
    }
    *(bf16x8*)(Kre + s0)     = outr0;
    *(bf16x8*)(Kre + s0 + 8) = outr1;
    *(bf16x8*)(Kim + s0)     = outi0;
    *(bf16x8*)(Kim + s0 + 8) = outi1;
}

// ---------------------------------------------------------------------------
// Workspace (bf16): FtabT[772*768] | GT[768*800] | WT[3*768*768]
//  | x16[16384*768] | CTs[2316*768] | spec[3*772*16384]; O overlays specV/Q.
// ---------------------------------------------------------------------------
extern "C" void kernel_launch(void* const* d_in, const int* in_sizes, int n_in,
                              void* d_out, int out_size, void* d_ws, size_t ws_size,
                              hipStream_t stream) {
    const float* x    = (const float*)d_in[0];
    const float* Wk   = (const float*)d_in[1];
    const float* Wv   = (const float*)d_in[2];
    const float* Wq   = (const float*)d_in[3];
    const float* gain = (const float*)d_in[4];
    float* out = (float*)d_out;

    __bf16* FtabT = (__bf16*)d_ws;
    __bf16* GT    = FtabT + (size_t)NSP * D_DIM;
    __bf16* WT    = GT    + (size_t)D_DIM * KP5;
    __bf16* x16   = WT    + (size_t)3 * D_DIM * D_DIM;
    __bf16* CTs   = x16   + (size_t)MROWS * D_DIM;
    __bf16* spec  = CTs   + (size_t)3 * NSP * D_DIM;
    __bf16* O     = spec  + SPECZ;   // over specV/specQ (free after scan)

    // prologue: tables + W transposes + x conversion (one dispatch)
    prologue<<<3264, 256, 0, stream>>>(FtabT, GT, Wk, Wv, Wq, WT, x, x16);

    // stage 2: CTs[z*772+c][e] = FtabT @ WT_z^T  (z-batched, stacked in M)
    mfma_nt<<<dim3(6, 7, 3), 256, 0, stream>>>(
        FtabT, WT, CTs, NSP, D_DIM, D_DIM,
        D_DIM, D_DIM, D_DIM,
        0L, (long)D_DIM * D_DIM, (long)NSP * D_DIM, 1, nullptr, nullptr);

    // stage 3: spec[2316][16384] = CTs @ x16^T — 128x256 triple-buffer kernel.
    // grid = 64 col-blocks x 19 row-blocks = 1216 (multiple of 8 for T1).
    mfma_nt256<<<dim3(64 * 19), 512, 0, stream>>>(
        CTs, x16, spec, 3 * NSP, MROWS, D_DIM,
        D_DIM, D_DIM, MROWS, 19, 1, nullptr, nullptr);

    // stage 4: causal binding scan + unbind (in place over specK)
    scan_blocks<<<BATCH * NF, 256, 0, stream>>>(spec);

    // OT -> O bf16 [16384][800] (zero-padded cols)
    transposeO64<<<dim3(MROWS / 64, 13), 256, 0, stream>>>(
        (const unsigned short*)spec, (unsigned short*)O);

    // stage 5: out[16384][768] = x + gain * (O @ GT^T) — same kernel.
    // grid = 3 col-blocks x 128 row-blocks = 384; O panels re-read 3x.
    mfma_nt256<<<dim3(3 * 128), 512, 0, stream>>>(
        O, GT, out, MROWS, D_DIM, KP5,
        KP5, KP5, D_DIM, 128, 0, x, gain);
}

// Round 14
// 260.610 us; speedup vs baseline: 3.2516x; 1.0465x over previous
//
#include <hip/hip_runtime.h>
#include <math.h>

#define D_DIM 768
#define NF    385
#define NSP   772          // 2*NF pad-to-4
#define BATCH 4
#define SEQ   4096
#define MROWS 16384
#define KP5   800          // stage-5 K padded to multiple of 32 (25 K-tiles)
#define SPECZ ((size_t)NSP * MROWS)

typedef __bf16 bf16x8 __attribute__((ext_vector_type(8)));
typedef float  f32x4  __attribute__((ext_vector_type(4)));

// async global->LDS, 16B per lane; LDS dest is wave-uniform base + lane*16
__device__ __forceinline__ void gl2lds16(const __bf16* g, __bf16* l) {
    __builtin_amdgcn_global_load_lds(
        (const __attribute__((address_space(1))) void*)g,
        (__attribute__((address_space(3))) void*)l, 16, 0, 0);
}

// ---------------------------------------------------------------------------
// Prologue A (one dispatch, 2 independent jobs partitioned by blockIdx):
//  [0,1728): transposeW — W_z [768][768] fp32 -> WT[z][d][e] bf16
//  [1728,2240): build DFT tables FtabT [772][768] + GT [768][800]
// (cvt_x moved to the s2_cvt dispatch: it has no consumer before stage-3
//  and co-scheduling it with the 126-block stage-2 GEMM fills idle CUs.)
// ---------------------------------------------------------------------------
__global__ __launch_bounds__(256) void prologue(
    __bf16* __restrict__ FtabT, __bf16* __restrict__ GT,
    const float* __restrict__ W0, const float* __restrict__ W1,
    const float* __restrict__ W2, __bf16* __restrict__ WT)
{
    const int bid = blockIdx.x;
    const int tid = threadIdx.x;
    if (bid < 1728) {
        // ---- transposeW ----
        __shared__ float tile[32][33];
        const int bz = bid / 576, rem = bid % 576;
        const int bx = rem % 24, by = rem / 24;
        const float* W = bz == 0 ? W0 : (bz == 1 ? W1 : W2);
        const int tx = tid & 31, ty = tid >> 5;
        const int e0 = bx * 32, d0 = by * 32;
        #pragma unroll
        for (int j = 0; j < 4; ++j)
            tile[ty + j*8][tx] = W[(size_t)(e0 + ty + j*8) * D_DIM + d0 + tx];
        __syncthreads();
        __bf16* WTz = WT + (size_t)bz * D_DIM * D_DIM;
        #pragma unroll
        for (int j = 0; j < 4; ++j)
            WTz[(size_t)(d0 + ty + j*8) * D_DIM + e0 + tx] = (__bf16)tile[tx][ty + j*8];
    } else {
        // ---- build tables ----
        int idx = (bid - 1728) * 256 + tid;
        const int stride = 512 * 256;
        const float w0 = 6.28318530717958647692f / (float)D_DIM;
        for (int i = idx; i < NF * D_DIM; i += stride) {
            int f = i / D_DIM, e = i - f * D_DIM;
            int m = (e * f) % D_DIM;             // exact angle reduction
            float s, c;
            __sincosf(w0 * (float)m, &s, &c);
            FtabT[(size_t)(2*f)   * D_DIM + e] = (__bf16)c;
            FtabT[(size_t)(2*f+1) * D_DIM + e] = (__bf16)(-s);
            bool dcny = (f == 0) || (f == NF - 1);
            float w = dcny ? (1.0f / D_DIM) : (2.0f / D_DIM);
            GT[(size_t)e * KP5 + 2*f]     = (__bf16)(w * c);
            GT[(size_t)e * KP5 + 2*f + 1] = dcny ? (__bf16)0.0f : (__bf16)(-w * s);
        }
        for (int i = idx; i < 2 * D_DIM; i += stride)
            FtabT[(size_t)770 * D_DIM + i] = (__bf16)0.0f;
        for (int i = idx; i < D_DIM * (KP5 - 2 * NF); i += stride) {
            int r = i / (KP5 - 2 * NF), c = 2 * NF + (i % (KP5 - 2 * NF));
            GT[(size_t)r * KP5 + c] = (__bf16)0.0f;
        }
    }
}

// ---------------------------------------------------------------------------
// s2_cvt (one dispatch, 2 independent jobs partitioned by blockIdx):
//  [0,126): stage-2 GEMM CTs[z*772+c][e] = FtabT @ WT_z^T — the 128x128
//           m97-structure GEMM body (verbatim math from mfma_nt, c_bf16
//           path) with bx=bid%6, by=(bid/6)%7, bz=bid/42.
//  [126,1150): cvt_x — x fp32 [16384][768] -> bf16 flat (1024 blocks).
// Rationale: stage-2 alone is 126 blocks (half the chip idle, latency
// bound); cvt_x is independent memory-bound work that fills the gap.
// ---------------------------------------------------------------------------
__global__ __launch_bounds__(256) void s2_cvt(
    const __bf16* __restrict__ FtabT, const __bf16* __restrict__ WT,
    __bf16* __restrict__ CTs,
    const float* __restrict__ x, __bf16* __restrict__ x16)
{
    const int bid = blockIdx.x;
    const int tid = threadIdx.x;
    if (bid >= 126) {
        // ---- cvt_x ----
        int idx = (bid - 126) * 256 + tid;
        const int stride = 1024 * 256;
        const int total8 = MROWS * D_DIM / 8;
        const float4* x4 = (const float4*)x;
        for (int i = idx; i < total8; i += stride) {
            float4 a = x4[2*i], b = x4[2*i+1];
            bf16x8 o;
            o[0]=(__bf16)a.x; o[1]=(__bf16)a.y; o[2]=(__bf16)a.z; o[3]=(__bf16)a.w;
            o[4]=(__bf16)b.x; o[5]=(__bf16)b.y; o[6]=(__bf16)b.z; o[7]=(__bf16)b.w;
            *((bf16x8*)x16 + i) = o;
        }
        return;
    }
    // ---- stage-2 GEMM: M=772 (z-local), N=768, K=768 ----
    const int M = NSP, K = D_DIM;
    const int lda = D_DIM, ldb = D_DIM, ldc = D_DIM;
    __shared__ __bf16 As[128 * 32];
    __shared__ __bf16 Bs[128 * 32];
    const int wave = tid >> 6, lane = tid & 63;
    const int lrow = lane & 15, lquad = lane >> 4;
    const int wm = wave >> 1, wn = wave & 1;
    const int bx = bid % 6, rem = bid / 6;
    const int by = rem % 7, bz = rem / 7;
    const int m0 = by * 128, n0 = bx * 128;
    const __bf16* Az = FtabT;
    const __bf16* Bz = WT + (size_t)bz * D_DIM * D_DIM;

    const int sr = tid >> 2;                               // 0..63
    const int sc = (((tid & 3) ^ ((tid >> 3) & 3))) * 8;   // swizzled K-block
    int ra0 = m0 + sr;      if (ra0 > M - 1) ra0 = M - 1;
    int ra1 = m0 + sr + 64; if (ra1 > M - 1) ra1 = M - 1;
    const int rb0 = n0 + sr, rb1 = n0 + sr + 64;
    __bf16* ldsA0 = As + wave * 512;
    __bf16* ldsA1 = As + 2048 + wave * 512;
    __bf16* ldsB0 = Bs + wave * 512;
    __bf16* ldsB1 = Bs + 2048 + wave * 512;

    const int swz = (lrow >> 1) & 3;                       // reader de-swizzle
    const int fragcol = (lquad ^ swz) * 8;

    f32x4 acc[4][4];
    #pragma unroll
    for (int i = 0; i < 4; ++i)
        #pragma unroll
        for (int j = 0; j < 4; ++j)
            acc[i][j] = (f32x4){0.f, 0.f, 0.f, 0.f};

    for (int k0 = 0; k0 < K; k0 += 32) {
        gl2lds16(Az + (size_t)ra0 * lda + k0 + sc, ldsA0);
        gl2lds16(Az + (size_t)ra1 * lda + k0 + sc, ldsA1);
        gl2lds16(Bz + (size_t)rb0 * ldb + k0 + sc, ldsB0);
        gl2lds16(Bz + (size_t)rb1 * ldb + k0 + sc, ldsB1);
        __syncthreads();
        bf16x8 af[4], bfr[4];
        #pragma unroll
        for (int i = 0; i < 4; ++i) {
            af[i]  = *(const bf16x8*)&As[(wm*64 + i*16 + lrow) * 32 + fragcol];
            bfr[i] = *(const bf16x8*)&Bs[(wn*64 + i*16 + lrow) * 32 + fragcol];
        }
        #pragma unroll
        for (int i = 0; i < 4; ++i)
            #pragma unroll
            for (int j = 0; j < 4; ++j)
                acc[i][j] = __builtin_amdgcn_mfma_f32_16x16x32_bf16(
                    af[i], bfr[j], acc[i][j], 0, 0, 0);
        __syncthreads();
    }

    // C/D layout (verified m89): col = lane&15, row = (lane>>4)*4 + reg
    const int colb = n0 + wn * 64 + lrow;
    const int rowb = m0 + wm * 64 + lquad * 4;
    __bf16* C = CTs + (size_t)bz * NSP * D_DIM;
    #pragma unroll
    for (int i = 0; i < 4; ++i)
        #pragma unroll
        for (int j = 0; j < 4; ++j) {
            const int col = colb + j * 16;
            #pragma unroll
            for (int r = 0; r < 4; ++r) {
                const int mm = rowb + i * 16 + r;
                if (mm < M) C[(size_t)mm * ldc + col] = (__bf16)acc[i][j][r];
            }
        }
}

// ---------------------------------------------------------------------------
// OT bf16 [772][16384] -> O bf16 [16384][800]; 64x64 tiles, 4-B packed
// accesses both sides. Rows >= 772 and O cols 772..799 read as zero.
// ---------------------------------------------------------------------------
__global__ __launch_bounds__(256) void transposeO64(
    const unsigned short* __restrict__ OT, unsigned short* __restrict__ O)
{
    __shared__ unsigned short tile[64][66];
    const int tid = threadIdx.x;
    const int m0 = blockIdx.x * 64, c0 = blockIdx.y * 64;
    const int half = tid & 31, row8 = tid >> 5;     // 32 col-pairs x 8 rows
    #pragma unroll
    for (int p = 0; p < 8; ++p) {
        const int c = c0 + p * 8 + row8;
        unsigned int v = 0;
        if (c < NSP)
            v = *(const unsigned int*)(OT + (size_t)c * MROWS + m0 + half * 2);
        *(unsigned int*)&tile[p * 8 + row8][half * 2] = v;
    }
    __syncthreads();
    #pragma unroll
    for (int p = 0; p < 8; ++p) {
        const int m = m0 + p * 8 + row8;
        const int c = c0 + half * 2;
        if (c < KP5) {
            unsigned int re = tile[half * 2][p * 8 + row8];
            unsigned int im = tile[half * 2 + 1][p * 8 + row8];
            *(unsigned int*)(O + (size_t)m * KP5 + c) = (im << 16) | re;
        }
    }
}

// ---------------------------------------------------------------------------
// 128x256 bf16 NT MFMA GEMM, triple-buffered 2-tile-deep prefetch, 2 blk/CU.
// R10-verified best (stage-3 77 us). R12 lesson: (512,4)=128 regs is the
// minimum viable budget for the 64-reg accumulator; deeper occupancy spills.
// 8 waves (2M x 4N, per-wave 64x64, acc[4][4]=64 AGPR), BK=32, 72 KiB LDS
// (A: 3 buf x 128x32; B: 3 buf x 256x32), 3 DMA ops/tile, ONE barrier per
// K-tile. Tile t stages tile t+2 into buf (t+2)%3 (t>=1; prologue staged
// tiles 0,1,2). vmcnt ledger: prologue 9 ops, vmcnt(6) lands tile 0; at
// each tile end in-flight = {t+1,t+2} = 6 -> vmcnt(3) drains t+1.
// Swizzle = m97 pair (2-way bank aliasing, free, m136).
// Grid: 1-D, ncol*nyb blocks, multiple of 8 (XCD swizzle).
// ---------------------------------------------------------------------------
__global__ __launch_bounds__(512, 4) void mfma_nt256(
    const __bf16* __restrict__ A, const __bf16* __restrict__ B,
    void* __restrict__ Cv, int M, int N, int K,
    int lda, int ldb, int ldc, int nyb, int c_bf16,
    const float* __restrict__ addend, const float* __restrict__ gain)
{
    __shared__ __bf16 lds[36864];          // 72 KiB
    __bf16* AsBase = lds;                  // 3 x [128][32]
    __bf16* BsBase = lds + 12288;          // 3 x [256][32]

    const int tid  = threadIdx.x;
    const int wave = tid >> 6, lane = tid & 63;
    const int lrow = lane & 15, lq = lane >> 4;
    const int wm = wave >> 2, wn = wave & 3;  // 2M x 4N waves

    // XCD-aware bijective swizzle (gridDim.x % 8 == 0 guaranteed by caller)
    const int cpx = gridDim.x >> 3;
    const int swz = (blockIdx.x & 7) * cpx + (blockIdx.x >> 3);
    const int bx = swz / nyb, by = swz - bx * nyb;
    const int m0 = by * 128, n0 = bx * 256;
    const int NT = K >> 5;

    // ---- staging constants (1 gl2lds op per thread per 128-row panel) ----
    const int srow = tid >> 2;                          // 0..127
    const int skc  = ((tid & 3) ^ ((tid >> 3) & 3)) * 8;  // inv-swizzled src col
    const int sdst = wave << 9;                         // wave-uniform, elems

    auto stageA = [&](int t, int buf) {
        __bf16* slot = AsBase + buf * 4096;
        int gr = m0 + srow;
        if (gr > M - 1) gr = M - 1;                     // M-tail clamp
        gl2lds16(A + (size_t)gr * lda + (t << 5) + skc, slot + sdst);
    };
    auto stageB = [&](int t, int buf) {
        __bf16* slot = BsBase + buf * 8192;
        #pragma unroll
        for (int h = 0; h < 2; ++h) {
            const int gr = n0 + h * 128 + srow;
            gl2lds16(B + (size_t)gr * ldb + (t << 5) + skc,
                     slot + h * 4096 + sdst);
        }
    };

    // ---- fragment-read constants ----
    const int kx   = (lq ^ ((lrow >> 1) & 3)) * 8;      // swizzled read col
    const int aoff = wm * 2048 + lrow * 32 + kx;
    const int boff = wn * 2048 + lrow * 32 + kx;

    bf16x8 Af[4], Bf[4];
    f32x4 acc[4][4];
    #pragma unroll
    for (int i = 0; i < 4; ++i)
        #pragma unroll
        for (int j = 0; j < 4; ++j)
            acc[i][j] = (f32x4){0.f, 0.f, 0.f, 0.f};

    // ---- prologue: stage tiles 0,1,2 into bufs 0,1,2; wait tile0 only ----
    stageA(0, 0); stageB(0, 0);
    if (NT > 1) { stageA(1, 1); stageB(1, 1); }
    if (NT > 2) { stageA(2, 2); stageB(2, 2); }
    if (NT > 2)      asm volatile("s_waitcnt vmcnt(6)" ::: "memory");
    else if (NT > 1) asm volatile("s_waitcnt vmcnt(3)" ::: "memory");
    else             asm volatile("s_waitcnt vmcnt(0)" ::: "memory");
    __builtin_amdgcn_s_barrier();
    __builtin_amdgcn_sched_barrier(0);

    // ---- main loop: 1 phase + 1 barrier per K-tile ----
    int br = 0;                                         // buffer of tile t
    for (int t = 0; t < NT; ++t) {
        const __bf16* Ard = AsBase + br * 4096;
        const __bf16* Brd = BsBase + br * 8192;

        #pragma unroll
        for (int ii = 0; ii < 4; ++ii)
            Af[ii] = *(const bf16x8*)(Ard + aoff + ii * 512);
        #pragma unroll
        for (int jj = 0; jj < 4; ++jj)
            Bf[jj] = *(const bf16x8*)(Brd + boff + jj * 512);

        if (t > 0 && t + 2 < NT) {                      // tile 2 staged in prologue
            int b2 = br + 2; if (b2 >= 3) b2 -= 3;      // buf of t+2
            stageA(t + 2, b2); stageB(t + 2, b2);
        }

        __builtin_amdgcn_s_setprio(1);
        #pragma unroll
        for (int ii = 0; ii < 4; ++ii)
            #pragma unroll
            for (int jj = 0; jj < 4; ++jj)
                acc[ii][jj] = __builtin_amdgcn_mfma_f32_16x16x32_bf16(
                    Af[ii], Bf[jj], acc[ii][jj], 0, 0, 0);
        __builtin_amdgcn_s_setprio(0);

        if (t + 2 < NT)      asm volatile("s_waitcnt vmcnt(3)" ::: "memory");
        else if (t + 1 < NT) asm volatile("s_waitcnt vmcnt(0)" ::: "memory");
        __builtin_amdgcn_s_barrier();
        __builtin_amdgcn_sched_barrier(0);
        ++br; if (br >= 3) br -= 3;
    }

    // ---- epilogue: C/D layout col = lane&15, row = (lane>>4)*4 + reg ----
    const int colb = n0 + wn * 64 + lrow;
    const int rowb = m0 + wm * 64 + lq * 4;
    if (c_bf16) {
        __bf16* C = (__bf16*)Cv;
        #pragma unroll
        for (int i = 0; i < 4; ++i)
            #pragma unroll
            for (int j = 0; j < 4; ++j) {
                const int col = colb + j * 16;
                #pragma unroll
                for (int r = 0; r < 4; ++r) {
                    const int mm = rowb + i * 16 + r;
                    if (mm < M) C[(size_t)mm * ldc + col] = (__bf16)acc[i][j][r];
                }
            }
    } else {
        float* C = (float*)Cv;
        const float g = gain[0];
        #pragma unroll
        for (int i = 0; i < 4; ++i)
            #pragma unroll
            for (int j = 0; j < 4; ++j) {
                const int col = colb + j * 16;
                #pragma unroll
                for (int r = 0; r < 4; ++r) {
                    const int mm = rowb + i * 16 + r;
                    if (mm < M) {
                        const size_t off = (size_t)mm * ldc + col;
                        C[off] = addend[off] + g * acc[i][j][r];
                    }
                }
            }
    }
}

// ---------------------------------------------------------------------------
// Causal complex scan over bf16 spectra (transposed layout), in place over K.
// One block per (b,f) chain; thread t owns 16 consecutive s.
// ---------------------------------------------------------------------------
__global__ __launch_bounds__(256) void scan_blocks(__bf16* __restrict__ spec) {
    const int blk = blockIdx.x;
    const int b = blk / NF, f = blk % NF;
    const int tid = threadIdx.x;
    const int lane = tid & 63, wid = tid >> 6;
    const size_t colbase = (size_t)b * SEQ;
    __bf16* Kre = spec + (size_t)(2*f) * MROWS + colbase;
    __bf16* Kim = Kre + MROWS;
    const __bf16* Vre = Kre + SPECZ;
    const __bf16* Vim = Vre + MROWS;
    const __bf16* Qre = Kre + 2 * SPECZ;
    const __bf16* Qim = Qre + MROWS;
    const int s0 = tid * 16;

    bf16x8 kr0 = *(const bf16x8*)(Kre + s0), kr1 = *(const bf16x8*)(Kre + s0 + 8);
    bf16x8 ki0 = *(const bf16x8*)(Kim + s0), ki1 = *(const bf16x8*)(Kim + s0 + 8);
    bf16x8 vr0 = *(const bf16x8*)(Vre + s0), vr1 = *(const bf16x8*)(Vre + s0 + 8);
    bf16x8 vi0 = *(const bf16x8*)(Vim + s0), vi1 = *(const bf16x8*)(Vim + s0 + 8);

    float pr[16], pi[16];
    #pragma unroll
    for (int u = 0; u < 8; ++u) {
        float a = (float)kr0[u], bq = (float)ki0[u], c = (float)vr0[u], d = (float)vi0[u];
        pr[u] = a * c - bq * d;
        pi[u] = a * d + bq * c;
        float a1 = (float)kr1[u], b1 = (float)ki1[u], c1 = (float)vr1[u], d1 = (float)vi1[u];
        pr[8+u] = a1 * c1 - b1 * d1;
        pi[8+u] = a1 * d1 + b1 * c1;
    }
    #pragma unroll
    for (int j = 1; j < 16; ++j) { pr[j] += pr[j-1]; pi[j] += pi[j-1]; }
    const float totr = pr[15], toti = pi[15];

    float sr = totr, si = toti;
    #pragma unroll
    for (int d = 1; d < 64; d <<= 1) {
        float ur = __shfl_up(sr, d, 64);
        float ui = __shfl_up(si, d, 64);
        if (lane >= d) { sr += ur; si += ui; }
    }
    __shared__ float wsr[4], wsi[4];
    if (lane == 63) { wsr[wid] = sr; wsi[wid] = si; }
    __syncthreads();
    float baser = 0.f, basei = 0.f;
    #pragma unroll
    for (int w = 0; w < 3; ++w)
        if (w < wid) { baser += wsr[w]; basei += wsi[w]; }
    const float exr = baser + sr - totr;
    const float exi = basei + si - toti;

    bf16x8 qr0 = *(const bf16x8*)(Qre + s0), qr1 = *(const bf16x8*)(Qre + s0 + 8);
    bf16x8 qi0 = *(const bf16x8*)(Qim + s0), qi1 = *(const bf16x8*)(Qim + s0 + 8);
    bf16x8 outr0, outr1, outi0, outi1;
    #pragma unroll
    for (int u = 0; u < 8; ++u) {
        float mr = exr + pr[u],   mi = exi + pi[u];
        float qr = (float)qr0[u], qi = (float)qi0[u];
        outr0[u] = (__bf16)(mr * qr + mi * qi);
        outi0[u] = (__bf16)(mi * qr - mr * qi);
        float mr1 = exr + pr[8+u], mi1 = exi + pi[8+u];
        float qr_ = (float)qr1[u], qi_ = (float)qi1[u];
        outr1[u] = (__bf16)(mr1 * qr_ + mi1 * qi_);
        outi1[u] = (__bf16)(mi1 * qr_ - mr1 * qi_);
    }
    *(bf16x8*)(Kre + s0)     = outr0;
    *(bf16x8*)(Kre + s0 + 8) = outr1;
    *(bf16x8*)(Kim + s0)     = outi0;
    *(bf16x8*)(Kim + s0 + 8) = outi1;
}

// ---------------------------------------------------------------------------
// Workspace (bf16): FtabT[772*768] | GT[768*800] | WT[3*768*768]
//  | x16[16384*768] | CTs[2316*768] | spec[3*772*16384]; O overlays specV/Q.
// ---------------------------------------------------------------------------
extern "C" void kernel_launch(void* const* d_in, const int* in_sizes, int n_in,
                              void* d_out, int out_size, void* d_ws, size_t ws_size,
                              hipStream_t stream) {
    const float* x    = (const float*)d_in[0];
    const float* Wk   = (const float*)d_in[1];
    const float* Wv   = (const float*)d_in[2];
    const float* Wq   = (const float*)d_in[3];
    const float* gain = (const float*)d_in[4];
    float* out = (float*)d_out;

    __bf16* FtabT = (__bf16*)d_ws;
    __bf16* GT    = FtabT + (size_t)NSP * D_DIM;
    __bf16* WT    = GT    + (size_t)D_DIM * KP5;
    __bf16* x16   = WT    + (size_t)3 * D_DIM * D_DIM;
    __bf16* CTs   = x16   + (size_t)MROWS * D_DIM;
    __bf16* spec  = CTs   + (size_t)3 * NSP * D_DIM;
    __bf16* O     = spec  + SPECZ;   // over specV/specQ (free after scan)

    // prologue A: tables + W transposes
    prologue<<<2240, 256, 0, stream>>>(FtabT, GT, Wk, Wv, Wq, WT);

    // stage 2 GEMM (126 blocks) co-scheduled with cvt_x (1024 blocks)
    s2_cvt<<<1150, 256, 0, stream>>>(FtabT, WT, CTs, x, x16);

    // stage 3: spec[2316][16384] = CTs @ x16^T — 128x256 triple-buffer kernel.
    // grid = 64 col-blocks x 19 row-blocks = 1216 (multiple of 8 for T1).
    mfma_nt256<<<dim3(64 * 19), 512, 0, stream>>>(
        CTs, x16, spec, 3 * NSP, MROWS, D_DIM,
        D_DIM, D_DIM, MROWS, 19, 1, nullptr, nullptr);

    // stage 4: causal binding scan + unbind (in place over specK)
    scan_blocks<<<BATCH * NF, 256, 0, stream>>>(spec);

    // OT -> O bf16 [16384][800] (zero-padded cols)
    transposeO64<<<dim3(MROWS / 64, 13), 256, 0, stream>>>(
        (const unsigned short*)spec, (unsigned short*)O);

    // stage 5: out[16384][768] = x + gain * (O @ GT^T) — same kernel.
    // grid = 3 col-blocks x 128 row-blocks = 384; O panels re-read 3x.
    mfma_nt256<<<dim3(3 * 128), 512, 0, stream>>>(
        O, GT, out, MROWS, D_DIM, KP5,
        KP5, KP5, D_DIM, 128, 0, x, gain);
}